// Round 1
// baseline (427.664 us; speedup 1.0000x reference)
//
#include <hip/hip_runtime.h>
#include <hip/hip_bf16.h>
#include <math.h>

#define N 8192
#define F 133
#define H 256
#define MF 200
#define RH 512
#define DEPTH 3
#define N_RO 2
#define MAXDEG 128   // expected degree 32, binomial tail; 128 is ~17 sigma

// ---------------- h0 = X @ W_in + b_in  (8192x133 @ 133x256) ----------------
__global__ __launch_bounds__(256) void k_in(const float* __restrict__ X,
                                            const float* __restrict__ W,
                                            const float* __restrict__ b,
                                            float* __restrict__ hout) {
    __shared__ float xs[16][F];
    const int t = threadIdx.x;
    const int row0 = blockIdx.x * 16;
    for (int i = t; i < 16 * F; i += 256) {
        int r = i / F, f = i % F;
        xs[r][f] = X[(row0 + r) * F + f];
    }
    __syncthreads();
    float acc[16];
#pragma unroll
    for (int r = 0; r < 16; ++r) acc[r] = 0.f;
    for (int f = 0; f < F; ++f) {
        float w = W[f * H + t];
#pragma unroll
        for (int r = 0; r < 16; ++r) acc[r] = fmaf(xs[r][f], w, acc[r]);
    }
    float bb = b[t];
#pragma unroll
    for (int r = 0; r < 16; ++r) hout[(row0 + r) * H + t] = acc[r] + bb;
}

// ---------------- sparse index build from dense adjacency ----------------
__global__ __launch_bounds__(256) void k_scan(const float4* __restrict__ A4,
                                              int* __restrict__ cnt,
                                              int* __restrict__ colidx) {
    const int total = N / 4 * N;  // 16,777,216 float4s
    for (int i = blockIdx.x * blockDim.x + threadIdx.x; i < total;
         i += gridDim.x * blockDim.x) {
        float4 v = A4[i];
        int base = i * 4;
        float vv[4] = {v.x, v.y, v.z, v.w};
#pragma unroll
        for (int c = 0; c < 4; ++c) {
            if (vv[c] != 0.0f) {
                int idx = base + c;
                int row = idx >> 13;        // /N
                int col = idx & (N - 1);    // %N
                int pos = atomicAdd(&cnt[row], 1);
                if (pos < MAXDEG) colidx[row * MAXDEG + pos] = col;
            }
        }
    }
}

// ---------------- s_nei[i] = h[i]·wa_nei, s_self[i] = h[i]·wa_self ----------------
__global__ __launch_bounds__(256) void k_scores(const float* __restrict__ h,
                                                const float* __restrict__ Watt,
                                                float* __restrict__ s_nei,
                                                float* __restrict__ s_self) {
    const int lane = threadIdx.x & 63;
    const int wave = threadIdx.x >> 6;
    const int row = blockIdx.x * 4 + wave;
    const float4 hv = *reinterpret_cast<const float4*>(&h[row * H + lane * 4]);
    const float4 wn = *reinterpret_cast<const float4*>(&Watt[lane * 4]);
    const float4 ws = *reinterpret_cast<const float4*>(&Watt[H + lane * 4]);
    float an = hv.x * wn.x + hv.y * wn.y + hv.z * wn.z + hv.w * wn.w;
    float as = hv.x * ws.x + hv.y * ws.y + hv.z * ws.z + hv.w * ws.w;
    for (int off = 32; off > 0; off >>= 1) {
        an += __shfl_down(an, off);
        as += __shfl_down(as, off);
    }
    if (lane == 0) { s_nei[row] = an; s_self[row] = as; }
}

// ---------------- h_new[i] = sum_j sigmoid(ss[i]+sn[j]+b) * h[j] (sparse) ----------------
__global__ __launch_bounds__(256) void k_agg(const float* __restrict__ hin,
                                             const int* __restrict__ cnt,
                                             const int* __restrict__ colidx,
                                             const float* __restrict__ s_nei,
                                             const float* __restrict__ s_self,
                                             const float* __restrict__ b_att,
                                             float* __restrict__ hout) {
    __shared__ float wls[MAXDEG];
    __shared__ int jls[MAXDEG];
    const int i = blockIdx.x;
    const int t = threadIdx.x;
    int n = cnt[i];
    if (n > MAXDEG) n = MAXDEG;
    float ssi = s_self[i] + b_att[0];
    if (t < n) {
        int j = colidx[i * MAXDEG + t];
        jls[t] = j;
        wls[t] = 1.0f / (1.0f + __expf(-(ssi + s_nei[j])));
    }
    __syncthreads();
    float acc = 0.f;
    for (int k = 0; k < n; ++k) {
        acc = fmaf(wls[k], hin[jls[k] * H + t], acc);
    }
    hout[i * H + t] = acc;
}

// ---------------- h = relu(h @ W_node[d] + b_node[d])  (8192x256 @ 256x256) ----------------
__global__ __launch_bounds__(256) void k_node(const float* __restrict__ hin,
                                              const float* __restrict__ W,
                                              const float* __restrict__ b,
                                              float* __restrict__ hout) {
    __shared__ float xs[16][H];  // 16 KB
    const int t = threadIdx.x;
    const int row0 = blockIdx.x * 16;
    const float4* src = reinterpret_cast<const float4*>(&hin[row0 * H]);
    float4* dst = reinterpret_cast<float4*>(&xs[0][0]);
    for (int i = t; i < 16 * H / 4; i += 256) dst[i] = src[i];
    __syncthreads();
    float acc[16];
#pragma unroll
    for (int r = 0; r < 16; ++r) acc[r] = 0.f;
    for (int k = 0; k < H; ++k) {
        float w = W[k * H + t];
#pragma unroll
        for (int r = 0; r < 16; ++r) acc[r] = fmaf(xs[r][k], w, acc[r]);
    }
    float bb = b[t];
#pragma unroll
    for (int r = 0; r < 16; ++r) {
        float v = acc[r] + bb;
        hout[(row0 + r) * H + t] = v > 0.f ? v : 0.f;
    }
}

// ---------------- g[t] += sum over 128 rows of h[.][t] ----------------
__global__ __launch_bounds__(256) void k_colsum(const float* __restrict__ h,
                                                float* __restrict__ g) {
    const int t = threadIdx.x;
    const int r0 = blockIdx.x * 128;
    float acc = 0.f;
    for (int r = 0; r < 128; ++r) acc += h[(r0 + r) * H + t];
    atomicAdd(&g[t], acc);
}

// ---------------- out[o] = relu(b[o] + sum_k in[k]*W[k*O+o]) ----------------
__global__ __launch_bounds__(256) void k_dense_relu(const float* __restrict__ in, int K,
                                                    const float* __restrict__ W,
                                                    const float* __restrict__ b,
                                                    float* __restrict__ out, int O) {
    __shared__ float xin[RH];
    const int o = blockIdx.x * 256 + threadIdx.x;
    for (int i = threadIdx.x; i < K; i += 256) xin[i] = in[i];
    __syncthreads();
    float acc = b[o];
    for (int k = 0; k < K; ++k) acc = fmaf(xin[k], W[k * O + o], acc);
    out[o] = acc > 0.f ? acc : 0.f;
}

// ---------------- scalar = b_out + g · W_out ----------------
__global__ __launch_bounds__(512) void k_out(const float* __restrict__ g,
                                             const float* __restrict__ W,
                                             const float* __restrict__ bo,
                                             float* __restrict__ out) {
    __shared__ float red[512];
    int t = threadIdx.x;
    red[t] = g[t] * W[t];
    __syncthreads();
    for (int s = 256; s > 0; s >>= 1) {
        if (t < s) red[t] += red[t + s];
        __syncthreads();
    }
    if (t == 0) out[0] = red[0] + bo[0];
}

extern "C" void kernel_launch(void* const* d_in, const int* in_sizes, int n_in,
                              void* d_out, int out_size, void* d_ws, size_t ws_size,
                              hipStream_t stream) {
    const float* A        = (const float*)d_in[0];
    const float* X        = (const float*)d_in[1];
    const float* mol      = (const float*)d_in[2];
    const float* W_in     = (const float*)d_in[3];
    const float* b_in     = (const float*)d_in[4];
    const float* W_att    = (const float*)d_in[5];
    const float* b_att    = (const float*)d_in[6];
    const float* W_node   = (const float*)d_in[7];
    const float* b_node   = (const float*)d_in[8];
    const float* W_ro_in  = (const float*)d_in[9];
    const float* b_ro_in  = (const float*)d_in[10];
    const float* W_ro_hid = (const float*)d_in[11];
    const float* b_ro_hid = (const float*)d_in[12];
    const float* W_out    = (const float*)d_in[13];
    const float* b_out    = (const float*)d_in[14];

    char* ws = (char*)d_ws;
    float* h_a    = (float*)(ws);                       // 8 MB
    float* h_b    = (float*)(ws + 8388608);             // 8 MB
    int*   colidx = (int*)  (ws + 16777216);            // 4 MB
    int*   cnt    = (int*)  (ws + 20971520);            // 32 KB
    float* s_nei  = (float*)(ws + 21004288);            // 32 KB
    float* s_self = (float*)(ws + 21037056);            // 32 KB
    float* g_in   = (float*)(ws + 21069824);            // 512 floats
    float* g_a    = (float*)(ws + 21071872);            // 512 floats
    float* g_b    = (float*)(ws + 21073920);            // 512 floats

    // counters and colsum target must be zeroed every call (ws not re-poisoned)
    hipMemsetAsync(cnt, 0, N * sizeof(int), stream);
    hipMemsetAsync(g_in, 0, H * sizeof(float), stream);

    k_in<<<N / 16, 256, 0, stream>>>(X, W_in, b_in, h_a);
    k_scan<<<4096, 256, 0, stream>>>((const float4*)A, cnt, colidx);

    float* cur = h_a;
    float* nxt = h_b;
    for (int d = 0; d < DEPTH; ++d) {
        k_scores<<<N / 4, 256, 0, stream>>>(cur, W_att, s_nei, s_self);
        k_agg<<<N, 256, 0, stream>>>(cur, cnt, colidx, s_nei, s_self, b_att, nxt);
        k_node<<<N / 16, 256, 0, stream>>>(nxt, W_node + (size_t)d * H * H,
                                           b_node + (size_t)d * H, cur);
    }

    k_colsum<<<64, 256, 0, stream>>>(cur, g_in);
    hipMemcpyAsync(g_in + H, mol, MF * sizeof(float), hipMemcpyDeviceToDevice, stream);

    k_dense_relu<<<RH / 256, 256, 0, stream>>>(g_in, H + MF, W_ro_in, b_ro_in, g_a, RH);
    k_dense_relu<<<RH / 256, 256, 0, stream>>>(g_a, RH, W_ro_hid, b_ro_hid, g_b, RH);
    k_dense_relu<<<RH / 256, 256, 0, stream>>>(g_b, RH, W_ro_hid + RH * RH,
                                               b_ro_hid + RH, g_a, RH);
    k_out<<<1, 512, 0, stream>>>(g_a, W_out, b_out, (float*)d_out);
}

// Round 2
// 411.109 us; speedup vs baseline: 1.0403x; 1.0403x over previous
//
#include <hip/hip_runtime.h>
#include <hip/hip_bf16.h>
#include <math.h>

#define N 8192
#define F 133
#define FP 136   // padded pitch for LDS
#define H 256
#define MF 200
#define RH 512
#define DEPTH 3
#define MAXDEG 128

// ---------------- h0 = X @ W_in + b_in  (8192x133 @ 133x256) ----------------
__global__ __launch_bounds__(256) void k_in(const float* __restrict__ X,
                                            const float* __restrict__ W,
                                            const float* __restrict__ b,
                                            float* __restrict__ hout) {
    __shared__ float xs[32][FP];
    const int t = threadIdx.x;
    const int row0 = blockIdx.x * 32;
    for (int i = t; i < 32 * F; i += 256) {
        int r = i / F, f = i - r * F;
        xs[r][f] = X[(row0 + r) * F + f];
    }
    __syncthreads();
    float acc[32];
#pragma unroll
    for (int r = 0; r < 32; ++r) acc[r] = 0.f;
    // 133 = 33*4 + 1
    for (int f = 0; f < 132; f += 4) {
        float w0 = W[(f + 0) * H + t];
        float w1 = W[(f + 1) * H + t];
        float w2 = W[(f + 2) * H + t];
        float w3 = W[(f + 3) * H + t];
#pragma unroll
        for (int r = 0; r < 32; ++r) {
            float4 xv = *reinterpret_cast<const float4*>(&xs[r][f]);
            acc[r] = fmaf(xv.x, w0, acc[r]);
            acc[r] = fmaf(xv.y, w1, acc[r]);
            acc[r] = fmaf(xv.z, w2, acc[r]);
            acc[r] = fmaf(xv.w, w3, acc[r]);
        }
    }
    {
        float w0 = W[132 * H + t];
#pragma unroll
        for (int r = 0; r < 32; ++r) acc[r] = fmaf(xs[r][132], w0, acc[r]);
    }
    float bb = b[t];
#pragma unroll
    for (int r = 0; r < 32; ++r) hout[(row0 + r) * H + t] = acc[r] + bb;
}

// ---------------- sparse index build: wave-per-row ballot compaction ----------------
__global__ __launch_bounds__(256) void k_scan(const float4* __restrict__ A4,
                                              int* __restrict__ cnt,
                                              int* __restrict__ colidx) {
    const int wave = threadIdx.x >> 6;
    const int lane = threadIdx.x & 63;
    const int row = blockIdx.x * 4 + wave;
    const float4* rowp = A4 + (size_t)row * (N / 4);
    const unsigned long long lmask = (1ull << lane) - 1ull;
    int base = 0;
    int* rowout = colidx + row * MAXDEG;
    for (int it = 0; it < N / 4 / 64; ++it) {  // 32 iterations
        float4 v = rowp[it * 64 + lane];
        int col0 = (it * 64 + lane) * 4;
        float vv[4] = {v.x, v.y, v.z, v.w};
#pragma unroll
        for (int c = 0; c < 4; ++c) {
            bool nz = (vv[c] != 0.0f);
            unsigned long long m = __ballot(nz);
            if (nz) {
                int pos = base + __popcll(m & lmask);
                if (pos < MAXDEG) rowout[pos] = col0 + c;
            }
            base += __popcll(m);
        }
    }
    if (lane == 0) cnt[row] = base < MAXDEG ? base : MAXDEG;
}

// ---------------- attention scores ----------------
__global__ __launch_bounds__(256) void k_scores(const float* __restrict__ h,
                                                const float* __restrict__ Watt,
                                                float* __restrict__ s_nei,
                                                float* __restrict__ s_self) {
    const int lane = threadIdx.x & 63;
    const int wave = threadIdx.x >> 6;
    const int row = blockIdx.x * 4 + wave;
    const float4 hv = *reinterpret_cast<const float4*>(&h[row * H + lane * 4]);
    const float4 wn = *reinterpret_cast<const float4*>(&Watt[lane * 4]);
    const float4 ws = *reinterpret_cast<const float4*>(&Watt[H + lane * 4]);
    float an = hv.x * wn.x + hv.y * wn.y + hv.z * wn.z + hv.w * wn.w;
    float as = hv.x * ws.x + hv.y * ws.y + hv.z * ws.z + hv.w * ws.w;
    for (int off = 32; off > 0; off >>= 1) {
        an += __shfl_down(an, off);
        as += __shfl_down(as, off);
    }
    if (lane == 0) { s_nei[row] = an; s_self[row] = as; }
}

// ---------------- sparse aggregate ----------------
__global__ __launch_bounds__(256) void k_agg(const float* __restrict__ hin,
                                             const int* __restrict__ cnt,
                                             const int* __restrict__ colidx,
                                             const float* __restrict__ s_nei,
                                             const float* __restrict__ s_self,
                                             const float* __restrict__ b_att,
                                             float* __restrict__ hout) {
    __shared__ float wls[MAXDEG];
    __shared__ int jls[MAXDEG];
    const int i = blockIdx.x;
    const int t = threadIdx.x;
    int n = cnt[i];
    float ssi = s_self[i] + b_att[0];
    if (t < n) {
        int j = colidx[i * MAXDEG + t];
        jls[t] = j;
        wls[t] = 1.0f / (1.0f + __expf(-(ssi + s_nei[j])));
    }
    __syncthreads();
    float acc = 0.f;
    for (int k = 0; k < n; ++k) {
        acc = fmaf(wls[k], hin[jls[k] * H + t], acc);
    }
    hout[i * H + t] = acc;
}

// ---------------- h = relu(h @ W_node[d] + b)  register-tiled SGEMM ----------------
#define BM 64
#define BN 64
#define BK 32
__global__ __launch_bounds__(256) void k_node(const float* __restrict__ hin,
                                              const float* __restrict__ W,
                                              const float* __restrict__ b,
                                              float* __restrict__ hout) {
    __shared__ float As[BK][BM];  // transposed: As[k][m]
    __shared__ float Ws[BK][BN];  // Ws[k][n]
    const int tid = threadIdx.x;
    const int tx = tid & 15;
    const int ty = tid >> 4;
    const int m0 = tx * 4, n0 = ty * 4;
    const int brow = blockIdx.x * BM;
    const int bcol = blockIdx.y * BN;
    const int sm = tid & 63;    // A-stage row
    const int sk4 = tid >> 6;   // A-stage k-quad
    float acc[4][4] = {{0.f}};
    for (int k0 = 0; k0 < H; k0 += BK) {
#pragma unroll
        for (int half = 0; half < 2; ++half) {
            int kk = 4 * sk4 + 16 * half;
            float4 a = *reinterpret_cast<const float4*>(&hin[(brow + sm) * H + k0 + kk]);
            As[kk + 0][sm] = a.x;
            As[kk + 1][sm] = a.y;
            As[kk + 2][sm] = a.z;
            As[kk + 3][sm] = a.w;
        }
#pragma unroll
        for (int half = 0; half < 2; ++half) {
            int idx = tid + 256 * half;        // 0..511
            int kr = idx >> 4;                 // 0..31
            int nq = idx & 15;                 // 0..15
            float4 w = *reinterpret_cast<const float4*>(&W[(k0 + kr) * H + bcol + nq * 4]);
            *reinterpret_cast<float4*>(&Ws[kr][nq * 4]) = w;
        }
        __syncthreads();
#pragma unroll
        for (int k = 0; k < BK; ++k) {
            float4 av = *reinterpret_cast<const float4*>(&As[k][m0]);
            float4 wv = *reinterpret_cast<const float4*>(&Ws[k][n0]);
            float a[4] = {av.x, av.y, av.z, av.w};
            float w[4] = {wv.x, wv.y, wv.z, wv.w};
#pragma unroll
            for (int i = 0; i < 4; ++i)
#pragma unroll
                for (int j = 0; j < 4; ++j) acc[i][j] = fmaf(a[i], w[j], acc[i][j]);
        }
        __syncthreads();
    }
#pragma unroll
    for (int i = 0; i < 4; ++i) {
        float4 o;
        float* op = &o.x;
#pragma unroll
        for (int j = 0; j < 4; ++j) {
            float v = acc[i][j] + b[bcol + n0 + j];
            op[j] = v > 0.f ? v : 0.f;
        }
        *reinterpret_cast<float4*>(&hout[(brow + m0 + i) * H + bcol + n0]) = o;
    }
}

// ---------------- column-sum partials: 32 blocks x 256 rows ----------------
__global__ __launch_bounds__(256) void k_colsum(const float* __restrict__ h,
                                                float* __restrict__ part) {
    const int t = threadIdx.x;
    const int r0 = blockIdx.x * 256;
    float acc = 0.f;
    for (int r = 0; r < 256; ++r) acc += h[(r0 + r) * H + t];
    part[blockIdx.x * H + t] = acc;
}

// ---------------- readout layer 1: g=[colsum, mol] (K=456) -> relu(g@W+b) ----------------
__global__ __launch_bounds__(256) void k_ro1(const float* __restrict__ part,
                                             const float* __restrict__ mol,
                                             const float* __restrict__ W,
                                             const float* __restrict__ b,
                                             float* __restrict__ out) {
    __shared__ float xin[H + MF];
    __shared__ float red[256];
    const int t = threadIdx.x;
    {
        float s = 0.f;
        for (int bb = 0; bb < 32; ++bb) s += part[bb * H + t];
        xin[t] = s;
    }
    if (t < MF) xin[H + t] = mol[t];
    __syncthreads();
    const int o = blockIdx.x * 64 + (t & 63);
    const int kg = t >> 6;
    float acc = 0.f;
    for (int k = kg; k < H + MF; k += 4) acc = fmaf(xin[k], W[k * RH + o], acc);
    red[t] = acc;
    __syncthreads();
    if (t < 64) {
        float v = red[t] + red[t + 64] + red[t + 128] + red[t + 192] + b[o];
        out[o] = v > 0.f ? v : 0.f;
    }
}

// ---------------- readout hidden layer (K=512) ----------------
__global__ __launch_bounds__(256) void k_ro_hid(const float* __restrict__ g,
                                                const float* __restrict__ W,
                                                const float* __restrict__ b,
                                                float* __restrict__ out) {
    __shared__ float xin[RH];
    __shared__ float red[256];
    const int t = threadIdx.x;
    xin[t] = g[t];
    xin[t + 256] = g[t + 256];
    __syncthreads();
    const int o = blockIdx.x * 64 + (t & 63);
    const int kg = t >> 6;
    float acc = 0.f;
    for (int k = kg; k < RH; k += 4) acc = fmaf(xin[k], W[k * RH + o], acc);
    red[t] = acc;
    __syncthreads();
    if (t < 64) {
        float v = red[t] + red[t + 64] + red[t + 128] + red[t + 192] + b[o];
        out[o] = v > 0.f ? v : 0.f;
    }
}

// ---------------- final dot ----------------
__global__ __launch_bounds__(512) void k_out(const float* __restrict__ g,
                                             const float* __restrict__ W,
                                             const float* __restrict__ bo,
                                             float* __restrict__ out) {
    __shared__ float red[512];
    int t = threadIdx.x;
    red[t] = g[t] * W[t];
    __syncthreads();
    for (int s = 256; s > 0; s >>= 1) {
        if (t < s) red[t] += red[t + s];
        __syncthreads();
    }
    if (t == 0) out[0] = red[0] + bo[0];
}

extern "C" void kernel_launch(void* const* d_in, const int* in_sizes, int n_in,
                              void* d_out, int out_size, void* d_ws, size_t ws_size,
                              hipStream_t stream) {
    const float* A        = (const float*)d_in[0];
    const float* X        = (const float*)d_in[1];
    const float* mol      = (const float*)d_in[2];
    const float* W_in     = (const float*)d_in[3];
    const float* b_in     = (const float*)d_in[4];
    const float* W_att    = (const float*)d_in[5];
    const float* b_att    = (const float*)d_in[6];
    const float* W_node   = (const float*)d_in[7];
    const float* b_node   = (const float*)d_in[8];
    const float* W_ro_in  = (const float*)d_in[9];
    const float* b_ro_in  = (const float*)d_in[10];
    const float* W_ro_hid = (const float*)d_in[11];
    const float* b_ro_hid = (const float*)d_in[12];
    const float* W_out    = (const float*)d_in[13];
    const float* b_out    = (const float*)d_in[14];

    char* ws = (char*)d_ws;
    float* h_a    = (float*)(ws);                       // 8 MB
    float* h_b    = (float*)(ws + 8388608);             // 8 MB
    int*   colidx = (int*)  (ws + 16777216);            // 4 MB
    int*   cnt    = (int*)  (ws + 20971520);            // 32 KB
    float* s_nei  = (float*)(ws + 21004288);            // 32 KB
    float* s_self = (float*)(ws + 21037056);            // 32 KB
    float* part   = (float*)(ws + 21069824);            // 32 KB
    float* g_a    = (float*)(ws + 21102592);            // 2 KB
    float* g_b    = (float*)(ws + 21104640);            // 2 KB

    k_in<<<N / 32, 256, 0, stream>>>(X, W_in, b_in, h_a);
    k_scan<<<N / 4, 256, 0, stream>>>((const float4*)A, cnt, colidx);

    float* cur = h_a;
    float* nxt = h_b;
    for (int d = 0; d < DEPTH; ++d) {
        k_scores<<<N / 4, 256, 0, stream>>>(cur, W_att, s_nei, s_self);
        k_agg<<<N, 256, 0, stream>>>(cur, cnt, colidx, s_nei, s_self, b_att, nxt);
        k_node<<<dim3(N / BM, H / BN), 256, 0, stream>>>(nxt, W_node + (size_t)d * H * H,
                                                         b_node + (size_t)d * H, cur);
    }

    k_colsum<<<32, 256, 0, stream>>>(cur, part);
    k_ro1<<<RH / 64, 256, 0, stream>>>(part, mol, W_ro_in, b_ro_in, g_a);
    k_ro_hid<<<RH / 64, 256, 0, stream>>>(g_a, W_ro_hid, b_ro_hid, g_b);
    k_ro_hid<<<RH / 64, 256, 0, stream>>>(g_b, W_ro_hid + RH * RH, b_ro_hid + RH, g_a);
    k_out<<<1, 512, 0, stream>>>(g_a, W_out, b_out, (float*)d_out);
}

// Round 3
// 379.998 us; speedup vs baseline: 1.1254x; 1.0819x over previous
//
#include <hip/hip_runtime.h>
#include <hip/hip_bf16.h>
#include <math.h>

#define N 8192
#define F 133
#define FP 136
#define H 256
#define MF 200
#define RH 512
#define DEPTH 3
#define MAXDEG 128

typedef unsigned short bfu;

static __device__ __forceinline__ bfu f2bf(float f) {
    unsigned u = __builtin_bit_cast(unsigned, f);
    u = (u + 0x7fff + ((u >> 16) & 1)) >> 16;   // RNE, finite inputs
    return (bfu)u;
}
static __device__ __forceinline__ float bf2f(bfu b) {
    unsigned u = (unsigned)b << 16;
    return __builtin_bit_cast(float, u);
}

// ---------------- h0 = X @ W_in + b_in  -> bf16 ----------------
__global__ __launch_bounds__(256) void k_in(const float* __restrict__ X,
                                            const float* __restrict__ W,
                                            const float* __restrict__ b,
                                            bfu* __restrict__ hout) {
    __shared__ float xs[32][FP];
    const int t = threadIdx.x;
    const int row0 = blockIdx.x * 32;
    for (int i = t; i < 32 * F; i += 256) {
        int r = i / F, f = i - r * F;
        xs[r][f] = X[(row0 + r) * F + f];
    }
    __syncthreads();
    float acc[32];
#pragma unroll
    for (int r = 0; r < 32; ++r) acc[r] = 0.f;
    for (int f = 0; f < 132; f += 4) {
        float w0 = W[(f + 0) * H + t];
        float w1 = W[(f + 1) * H + t];
        float w2 = W[(f + 2) * H + t];
        float w3 = W[(f + 3) * H + t];
#pragma unroll
        for (int r = 0; r < 32; ++r) {
            float4 xv = *reinterpret_cast<const float4*>(&xs[r][f]);
            acc[r] = fmaf(xv.x, w0, acc[r]);
            acc[r] = fmaf(xv.y, w1, acc[r]);
            acc[r] = fmaf(xv.z, w2, acc[r]);
            acc[r] = fmaf(xv.w, w3, acc[r]);
        }
    }
    {
        float w0 = W[132 * H + t];
#pragma unroll
        for (int r = 0; r < 32; ++r) acc[r] = fmaf(xs[r][132], w0, acc[r]);
    }
    float bb = b[t];
#pragma unroll
    for (int r = 0; r < 32; ++r) hout[(row0 + r) * H + t] = f2bf(acc[r] + bb);
}

// ---------------- sparse index build: wave-per-row ballot compaction ----------------
__global__ __launch_bounds__(256) void k_scan(const float4* __restrict__ A4,
                                              int* __restrict__ cnt,
                                              int* __restrict__ colidx) {
    const int wave = threadIdx.x >> 6;
    const int lane = threadIdx.x & 63;
    const int row = blockIdx.x * 4 + wave;
    const float4* rowp = A4 + (size_t)row * (N / 4);
    const unsigned long long lmask = (1ull << lane) - 1ull;
    int base = 0;
    int* rowout = colidx + row * MAXDEG;
    for (int it = 0; it < N / 4 / 64; ++it) {
        float4 v = rowp[it * 64 + lane];
        int col0 = (it * 64 + lane) * 4;
        float vv[4] = {v.x, v.y, v.z, v.w};
#pragma unroll
        for (int c = 0; c < 4; ++c) {
            bool nz = (vv[c] != 0.0f);
            unsigned long long m = __ballot(nz);
            if (nz) {
                int pos = base + __popcll(m & lmask);
                if (pos < MAXDEG) rowout[pos] = col0 + c;
            }
            base += __popcll(m);
        }
    }
    if (lane == 0) cnt[row] = base < MAXDEG ? base : MAXDEG;
}

// ---------------- attention scores (h in bf16) ----------------
__global__ __launch_bounds__(256) void k_scores(const bfu* __restrict__ h,
                                                const float* __restrict__ Watt,
                                                float* __restrict__ s_nei,
                                                float* __restrict__ s_self) {
    const int lane = threadIdx.x & 63;
    const int wave = threadIdx.x >> 6;
    const int row = blockIdx.x * 4 + wave;
    const ushort4 hv = *reinterpret_cast<const ushort4*>(&h[row * H + lane * 4]);
    const float4 wn = *reinterpret_cast<const float4*>(&Watt[lane * 4]);
    const float4 ws = *reinterpret_cast<const float4*>(&Watt[H + lane * 4]);
    float h0 = bf2f(hv.x), h1 = bf2f(hv.y), h2 = bf2f(hv.z), h3 = bf2f(hv.w);
    float an = h0 * wn.x + h1 * wn.y + h2 * wn.z + h3 * wn.w;
    float as = h0 * ws.x + h1 * ws.y + h2 * ws.z + h3 * ws.w;
    for (int off = 32; off > 0; off >>= 1) {
        an += __shfl_down(an, off);
        as += __shfl_down(as, off);
    }
    if (lane == 0) { s_nei[row] = an; s_self[row] = as; }
}

// ---------------- sparse aggregate: gather bf16 rows, write fp32 ----------------
__global__ __launch_bounds__(256) void k_agg(const bfu* __restrict__ hin,
                                             const int* __restrict__ cnt,
                                             const int* __restrict__ colidx,
                                             const float* __restrict__ s_nei,
                                             const float* __restrict__ s_self,
                                             const float* __restrict__ b_att,
                                             float* __restrict__ hout) {
    __shared__ float wls[MAXDEG];
    __shared__ int jls[MAXDEG];
    const int i = blockIdx.x;
    const int t = threadIdx.x;
    int n = cnt[i];
    float ssi = s_self[i] + b_att[0];
    if (t < n) {
        int j = colidx[i * MAXDEG + t];
        jls[t] = j;
        wls[t] = 1.0f / (1.0f + __expf(-(ssi + s_nei[j])));
    }
    __syncthreads();
    float a0 = 0.f, a1 = 0.f, a2 = 0.f, a3 = 0.f;
    int k = 0;
    for (; k + 4 <= n; k += 4) {
        a0 = fmaf(wls[k + 0], bf2f(hin[jls[k + 0] * H + t]), a0);
        a1 = fmaf(wls[k + 1], bf2f(hin[jls[k + 1] * H + t]), a1);
        a2 = fmaf(wls[k + 2], bf2f(hin[jls[k + 2] * H + t]), a2);
        a3 = fmaf(wls[k + 3], bf2f(hin[jls[k + 3] * H + t]), a3);
    }
    for (; k < n; ++k) a0 = fmaf(wls[k], bf2f(hin[jls[k] * H + t]), a0);
    hout[i * H + t] = (a0 + a1) + (a2 + a3);
}

// ---------------- h = relu(hg @ W + b): fp32 in, bf16 out ----------------
#define BM 64
#define BN 64
#define BK 32
__global__ __launch_bounds__(256) void k_node(const float* __restrict__ hin,
                                              const float* __restrict__ W,
                                              const float* __restrict__ b,
                                              bfu* __restrict__ hout) {
    __shared__ float As[BK][BM];
    __shared__ float Ws[BK][BN];
    const int tid = threadIdx.x;
    const int tx = tid & 15;
    const int ty = tid >> 4;
    const int m0 = tx * 4, n0 = ty * 4;
    const int brow = blockIdx.x * BM;
    const int bcol = blockIdx.y * BN;
    const int sm = tid & 63;
    const int sk4 = tid >> 6;
    float acc[4][4] = {{0.f}};
    for (int k0 = 0; k0 < H; k0 += BK) {
#pragma unroll
        for (int half = 0; half < 2; ++half) {
            int kk = 4 * sk4 + 16 * half;
            float4 a = *reinterpret_cast<const float4*>(&hin[(brow + sm) * H + k0 + kk]);
            As[kk + 0][sm] = a.x;
            As[kk + 1][sm] = a.y;
            As[kk + 2][sm] = a.z;
            As[kk + 3][sm] = a.w;
        }
#pragma unroll
        for (int half = 0; half < 2; ++half) {
            int idx = tid + 256 * half;
            int kr = idx >> 4;
            int nq = idx & 15;
            float4 w = *reinterpret_cast<const float4*>(&W[(k0 + kr) * H + bcol + nq * 4]);
            *reinterpret_cast<float4*>(&Ws[kr][nq * 4]) = w;
        }
        __syncthreads();
#pragma unroll
        for (int k = 0; k < BK; ++k) {
            float4 av = *reinterpret_cast<const float4*>(&As[k][m0]);
            float4 wv = *reinterpret_cast<const float4*>(&Ws[k][n0]);
            float a[4] = {av.x, av.y, av.z, av.w};
            float w[4] = {wv.x, wv.y, wv.z, wv.w};
#pragma unroll
            for (int i = 0; i < 4; ++i)
#pragma unroll
                for (int j = 0; j < 4; ++j) acc[i][j] = fmaf(a[i], w[j], acc[i][j]);
        }
        __syncthreads();
    }
#pragma unroll
    for (int i = 0; i < 4; ++i) {
        ushort4 o;
        float v0 = acc[i][0] + b[bcol + n0 + 0];
        float v1 = acc[i][1] + b[bcol + n0 + 1];
        float v2 = acc[i][2] + b[bcol + n0 + 2];
        float v3 = acc[i][3] + b[bcol + n0 + 3];
        o.x = f2bf(v0 > 0.f ? v0 : 0.f);
        o.y = f2bf(v1 > 0.f ? v1 : 0.f);
        o.z = f2bf(v2 > 0.f ? v2 : 0.f);
        o.w = f2bf(v3 > 0.f ? v3 : 0.f);
        *reinterpret_cast<ushort4*>(&hout[(brow + m0 + i) * H + bcol + n0]) = o;
    }
}

// ---------------- column-sum partials: 256 blocks x 32 rows ----------------
__global__ __launch_bounds__(256) void k_colsum(const bfu* __restrict__ h,
                                                float* __restrict__ part) {
    const int t = threadIdx.x;
    const int r0 = blockIdx.x * 32;
    float a0 = 0.f, a1 = 0.f;
#pragma unroll
    for (int r = 0; r < 32; r += 2) {
        a0 += bf2f(h[(r0 + r) * H + t]);
        a1 += bf2f(h[(r0 + r + 1) * H + t]);
    }
    part[blockIdx.x * H + t] = a0 + a1;
}

// ---------------- readout layer 1: g=[colsum, mol] (K=456) ----------------
__global__ __launch_bounds__(256) void k_ro1(const float* __restrict__ part,
                                             const float* __restrict__ mol,
                                             const float* __restrict__ W,
                                             const float* __restrict__ b,
                                             float* __restrict__ out) {
    __shared__ float xin[H + MF];
    __shared__ float red[256];
    const int t = threadIdx.x;
    {
        float s0 = 0.f, s1 = 0.f, s2 = 0.f, s3 = 0.f;
        for (int bb = 0; bb < 256; bb += 4) {
            s0 += part[(bb + 0) * H + t];
            s1 += part[(bb + 1) * H + t];
            s2 += part[(bb + 2) * H + t];
            s3 += part[(bb + 3) * H + t];
        }
        xin[t] = (s0 + s1) + (s2 + s3);
    }
    if (t < MF) xin[H + t] = mol[t];
    __syncthreads();
    const int o = blockIdx.x * 64 + (t & 63);
    const int kg = t >> 6;
    float acc = 0.f;
    for (int k = kg; k < H + MF; k += 4) acc = fmaf(xin[k], W[k * RH + o], acc);
    red[t] = acc;
    __syncthreads();
    if (t < 64) {
        float v = red[t] + red[t + 64] + red[t + 128] + red[t + 192] + b[o];
        out[o] = v > 0.f ? v : 0.f;
    }
}

// ---------------- readout hidden layer (K=512) ----------------
__global__ __launch_bounds__(256) void k_ro_hid(const float* __restrict__ g,
                                                const float* __restrict__ W,
                                                const float* __restrict__ b,
                                                float* __restrict__ out) {
    __shared__ float xin[RH];
    __shared__ float red[256];
    const int t = threadIdx.x;
    xin[t] = g[t];
    xin[t + 256] = g[t + 256];
    __syncthreads();
    const int o = blockIdx.x * 64 + (t & 63);
    const int kg = t >> 6;
    float acc = 0.f;
    for (int k = kg; k < RH; k += 4) acc = fmaf(xin[k], W[k * RH + o], acc);
    red[t] = acc;
    __syncthreads();
    if (t < 64) {
        float v = red[t] + red[t + 64] + red[t + 128] + red[t + 192] + b[o];
        out[o] = v > 0.f ? v : 0.f;
    }
}

// ---------------- final dot ----------------
__global__ __launch_bounds__(512) void k_out(const float* __restrict__ g,
                                             const float* __restrict__ W,
                                             const float* __restrict__ bo,
                                             float* __restrict__ out) {
    __shared__ float red[512];
    int t = threadIdx.x;
    red[t] = g[t] * W[t];
    __syncthreads();
    for (int s = 256; s > 0; s >>= 1) {
        if (t < s) red[t] += red[t + s];
        __syncthreads();
    }
    if (t == 0) out[0] = red[0] + bo[0];
}

extern "C" void kernel_launch(void* const* d_in, const int* in_sizes, int n_in,
                              void* d_out, int out_size, void* d_ws, size_t ws_size,
                              hipStream_t stream) {
    const float* A        = (const float*)d_in[0];
    const float* X        = (const float*)d_in[1];
    const float* mol      = (const float*)d_in[2];
    const float* W_in     = (const float*)d_in[3];
    const float* b_in     = (const float*)d_in[4];
    const float* W_att    = (const float*)d_in[5];
    const float* b_att    = (const float*)d_in[6];
    const float* W_node   = (const float*)d_in[7];
    const float* b_node   = (const float*)d_in[8];
    const float* W_ro_in  = (const float*)d_in[9];
    const float* b_ro_in  = (const float*)d_in[10];
    const float* W_ro_hid = (const float*)d_in[11];
    const float* b_ro_hid = (const float*)d_in[12];
    const float* W_out    = (const float*)d_in[13];
    const float* b_out    = (const float*)d_in[14];

    char* ws = (char*)d_ws;
    bfu*   hb     = (bfu*)  (ws);                       // 4 MB bf16 h
    float* hg     = (float*)(ws + 4194304);             // 8 MB fp32 agg out
    int*   colidx = (int*)  (ws + 12582912);            // 4 MB
    int*   cnt    = (int*)  (ws + 16777216);            // 32 KB
    float* s_nei  = (float*)(ws + 16809984);            // 32 KB
    float* s_self = (float*)(ws + 16842752);            // 32 KB
    float* part   = (float*)(ws + 16875520);            // 256 KB
    float* g_a    = (float*)(ws + 17137664);            // 2 KB
    float* g_b    = (float*)(ws + 17139712);            // 2 KB

    k_in<<<N / 32, 256, 0, stream>>>(X, W_in, b_in, hb);
    k_scan<<<N / 4, 256, 0, stream>>>((const float4*)A, cnt, colidx);

    for (int d = 0; d < DEPTH; ++d) {
        k_scores<<<N / 4, 256, 0, stream>>>(hb, W_att, s_nei, s_self);
        k_agg<<<N, 256, 0, stream>>>(hb, cnt, colidx, s_nei, s_self, b_att, hg);
        k_node<<<dim3(N / BM, H / BN), 256, 0, stream>>>(hg, W_node + (size_t)d * H * H,
                                                         b_node + (size_t)d * H, hb);
    }

    k_colsum<<<256, 256, 0, stream>>>(hb, part);
    k_ro1<<<RH / 64, 256, 0, stream>>>(part, mol, W_ro_in, b_ro_in, g_a);
    k_ro_hid<<<RH / 64, 256, 0, stream>>>(g_a, W_ro_hid, b_ro_hid, g_b);
    k_ro_hid<<<RH / 64, 256, 0, stream>>>(g_b, W_ro_hid + RH * RH, b_ro_hid + RH, g_a);
    k_out<<<1, 512, 0, stream>>>(g_a, W_out, b_out, (float*)d_out);
}